// Round 10
// baseline (718.982 us; speedup 1.0000x reference)
//
#include <hip/hip_runtime.h>
#include <hip/hip_bf16.h>

// Problem constants (from reference)
#define NU 100000
#define NI 50000
#define NE 1000000
#define NP 500000
// D_IN = D_HID = 128, D_OUT = 64

typedef unsigned short u16;
typedef unsigned int u32;
typedef __attribute__((ext_vector_type(8))) short short8;   // 8 bf16 (4 VGPRs)
typedef __attribute__((ext_vector_type(4))) float f32x4;

static __device__ __forceinline__ u16 f2bf(float f) {
    union { float f; u32 u; } x; x.f = f;
    u32 r = x.u + 0x7fff + ((x.u >> 16) & 1);   // round-to-nearest-even
    return (u16)(r >> 16);
}
static __device__ __forceinline__ float bf2f(u16 h) {
    union { u32 u; float f; } x; x.u = ((u32)h) << 16;
    return x.f;
}

// ---------------- f32 -> bf16 table conversion ----------------
__global__ __launch_bounds__(256) void cvt_kernel(const float* __restrict__ in,
                                                  u16* __restrict__ out, int n8) {
    int i = blockIdx.x * blockDim.x + threadIdx.x;
    if (i >= n8) return;
    float4 a = ((const float4*)in)[2 * i];
    float4 b = ((const float4*)in)[2 * i + 1];
    ushort4 lo = {f2bf(a.x), f2bf(a.y), f2bf(a.z), f2bf(a.w)};
    ushort4 hi = {f2bf(b.x), f2bf(b.y), f2bf(b.z), f2bf(b.w)};
    ((ushort4*)out)[2 * i]     = lo;
    ((ushort4*)out)[2 * i + 1] = hi;
}

// ---------------- weight transpose+cast: Wt[n][0:128]=Wn[:,n], Wt[n][128:256]=Ws[:,n] ----
__global__ void wtrans_kernel(const float* __restrict__ Wn, const float* __restrict__ Ws,
                              u16* __restrict__ Wt, int N) {
    int n = blockIdx.x;
    int k = threadIdx.x;   // blockDim = 128
    Wt[(size_t)n * 256 + k]       = f2bf(Wn[(size_t)k * N + n]);
    Wt[(size_t)n * 256 + 128 + k] = f2bf(Ws[(size_t)k * N + n]);
}

// ---------------- CSR build ----------------

__global__ void hist_kernel(const int* __restrict__ dst, int* __restrict__ deg, int E) {
    int e = blockIdx.x * blockDim.x + threadIdx.x;
    if (e < E) atomicAdd(&deg[__builtin_nontemporal_load(&dst[e])], 1);
}

__global__ void scan_local_kernel(const int* __restrict__ in, int* __restrict__ out,
                                  int* __restrict__ bsum, int n) {
    __shared__ int s[1024];
    int i = blockIdx.x * 1024 + threadIdx.x;
    int v = (i < n) ? in[i] : 0;
    s[threadIdx.x] = v;
    __syncthreads();
    for (int off = 1; off < 1024; off <<= 1) {
        int t = (threadIdx.x >= off) ? s[threadIdx.x - off] : 0;
        __syncthreads();
        s[threadIdx.x] += t;
        __syncthreads();
    }
    if (i < n) out[i] = s[threadIdx.x] - v;   // exclusive within block
    if (threadIdx.x == 1023) bsum[blockIdx.x] = s[1023];
}

__global__ void scan_bsum_kernel(int* bsum, int nb) {
    __shared__ int s[1024];
    int v = (threadIdx.x < nb) ? bsum[threadIdx.x] : 0;
    s[threadIdx.x] = v;
    __syncthreads();
    for (int off = 1; off < 1024; off <<= 1) {
        int t = (threadIdx.x >= off) ? s[threadIdx.x - off] : 0;
        __syncthreads();
        s[threadIdx.x] += t;
        __syncthreads();
    }
    if (threadIdx.x < nb) bsum[threadIdx.x] = s[threadIdx.x] - v;  // exclusive
}

__global__ void scan_finalize_kernel(int* __restrict__ rs, const int* __restrict__ bsum,
                                     int* __restrict__ cursor, int n, int E) {
    int i = blockIdx.x * 1024 + threadIdx.x;
    if (i < n) {
        int v = rs[i] + bsum[blockIdx.x];
        rs[i] = v;
        cursor[i] = v;
    }
    if (i == 0) rs[n] = E;
}

// XCD-aligned dst-partitioned fill (window = blockIdx.x & 7 pins each csr
// window to one XCD's L2). Edge-stream reads are NON-TEMPORAL so the 8
// re-read passes don't evict partially-filled dirty csr lines (round-9
// profile: 38.8MB HBM writes for a 4MB buffer = read-stream evictions).
__global__ void fill_kernel(const int* __restrict__ src, const int* __restrict__ dst,
                            int* cursor, int* __restrict__ csr, int E, int n) {
    int window = blockIdx.x & 7;
    int e = (blockIdx.x >> 3) * blockDim.x + threadIdx.x;
    if (e >= E) return;
    int d = __builtin_nontemporal_load(&dst[e]);
    int chunk = (n + 7) >> 3;
    int lo = window * chunk;
    if (d >= lo && d < lo + chunk) {
        int p = atomicAdd(&cursor[d], 1);
        csr[p] = __builtin_nontemporal_load(&src[e]);
    }
}

// ---------------- fused mean-agg + conv (MFMA) + relu + row L2-norm ----------------
// Block = 256 threads = 4 waves, 64-row tile.
// Phase A: stage hd (self) half of A-tile, cols 128..255 (coalesced 16B).
// Phase B: each wave gathers+means neighbors for its 16 rows directly into
//          cols 0..127 of the LDS A-tile (16 lanes x ushort8 per edge-row,
//          4 edge slots, unroll x2; f32 accum -> bf16, identical rounding to
//          the former separate agg kernel).
// Phase C: MFMA over [agg | hd] @ Wt^T, bias+relu, row L2-norm, coalesced
//          transposed store through LDS.
template <int DOUT, bool WRITE_F32>
__global__ __launch_bounds__(256) void fused_conv_kernel(
    const u16* __restrict__ hsrc, const u16* __restrict__ hd,
    const int* __restrict__ rs, const int* __restrict__ csr,
    const u16* __restrict__ Wt, const float* __restrict__ bn,
    const float* __restrict__ bs, float* __restrict__ outf,
    u16* __restrict__ outb, int T)
{
    constexpr int NF   = DOUT / 64;               // col fragments per wave (2 or 1)
    constexpr int FSTR = (DOUT == 128) ? 132 : 68; // f32 out stride (16B-aligned rows)
    __shared__ u16 smA[64 * 264];                  // 33792 B, reused as f32 out
    __shared__ float psum[4][64];
    __shared__ float sinv[64];
    float* smF = (float*)smA;

    const int tid  = threadIdx.x;
    const int wave = tid >> 6;
    const int lane = tid & 63;
    const int lr   = lane & 15;
    const int lg   = lane >> 4;                    // 0..3
    const int t0   = blockIdx.x * 64;

    // ---- Phase A: stage hd half (cols 128..255), 64 rows x 16 chunks ----
    #pragma unroll
    for (int i = 0; i < 4; ++i) {
        int lin = i * 256 + tid;                   // 0..1023
        int row = lin >> 4;
        int c   = lin & 15;
        int t   = t0 + row; if (t >= T) t = T - 1; // clamp; stores guarded later
        *(short8*)&smA[row * 264 + 128 + (c << 3)] =
            *(const short8*)&hd[(size_t)t * 128 + (c << 3)];
    }

    // ---- Phase B: gather+mean into cols 0..127; wave w owns rows w*16..+15 ----
    for (int r = 0; r < 16; ++r) {
        int row = wave * 16 + r;
        int t = t0 + row;
        float acc[8] = {};
        int deg = 0;
        if (t < T) {
            int e0 = rs[t], e1 = rs[t + 1];
            deg = e1 - e0;
            int e = e0 + lg;
            for (; e + 4 < e1; e += 8) {
                int s0 = csr[e], s1 = csr[e + 4];
                short8 v0 = *(const short8*)&hsrc[(size_t)s0 * 128 + (lr << 3)];
                short8 v1 = *(const short8*)&hsrc[(size_t)s1 * 128 + (lr << 3)];
                #pragma unroll
                for (int q = 0; q < 8; ++q)
                    acc[q] += bf2f((u16)v0[q]) + bf2f((u16)v1[q]);
            }
            if (e < e1) {
                int s0 = csr[e];
                short8 v0 = *(const short8*)&hsrc[(size_t)s0 * 128 + (lr << 3)];
                #pragma unroll
                for (int q = 0; q < 8; ++q) acc[q] += bf2f((u16)v0[q]);
            }
        }
        #pragma unroll
        for (int q = 0; q < 8; ++q) {
            acc[q] += __shfl_xor(acc[q], 16);
            acc[q] += __shfl_xor(acc[q], 32);
        }
        if (lg == 0) {
            float inv = (deg > 0) ? 1.f / (float)deg : 0.f;
            short8 o;
            #pragma unroll
            for (int q = 0; q < 8; ++q) o[q] = (short)f2bf(acc[q] * inv);
            *(short8*)&smA[row * 264 + (lr << 3)] = o;
        }
    }
    __syncthreads();

    // ---- Phase C: MFMA ----
    const u16* wp[NF];
    float bias[NF];
    #pragma unroll
    for (int ni = 0; ni < NF; ++ni) {
        int col = wave * (16 * NF) + ni * 16 + lr;
        wp[ni] = Wt + (size_t)col * 256;
        bias[ni] = bn[col] + bs[col];
    }

    f32x4 acc[4][NF];
    #pragma unroll
    for (int mi = 0; mi < 4; ++mi)
        #pragma unroll
        for (int ni = 0; ni < NF; ++ni)
            acc[mi][ni] = (f32x4){0.f, 0.f, 0.f, 0.f};

    #pragma unroll
    for (int ks = 0; ks < 8; ++ks) {
        const int kb = ks * 32 + (lg << 3);
        short8 b[NF];
        #pragma unroll
        for (int ni = 0; ni < NF; ++ni) b[ni] = *(const short8*)&wp[ni][kb];
        #pragma unroll
        for (int mi = 0; mi < 4; ++mi) {
            short8 a = *(const short8*)&smA[(mi * 16 + lr) * 264 + kb];
            #pragma unroll
            for (int ni = 0; ni < NF; ++ni)
                acc[mi][ni] = __builtin_amdgcn_mfma_f32_16x16x32_bf16(a, b[ni], acc[mi][ni], 0, 0, 0);
        }
    }
    __syncthreads();   // all waves done reading smA before overwrite as f32

    // bias + relu; z -> LDS (transpose buffer); per-row partial square-sums
    float rsum[4][4];
    #pragma unroll
    for (int mi = 0; mi < 4; ++mi) {
        #pragma unroll
        for (int j = 0; j < 4; ++j) {
            int rowg = mi * 16 + lg * 4 + j;
            float s = 0.f;
            #pragma unroll
            for (int ni = 0; ni < NF; ++ni) {
                float z = fmaxf(acc[mi][ni][j] + bias[ni], 0.f);
                int colg = wave * (16 * NF) + ni * 16 + lr;
                smF[rowg * FSTR + colg] = z;
                s = fmaf(z, z, s);
            }
            rsum[mi][j] = s;
        }
    }
    #pragma unroll
    for (int m = 1; m < 16; m <<= 1)
        #pragma unroll
        for (int mi = 0; mi < 4; ++mi)
            #pragma unroll
            for (int j = 0; j < 4; ++j)
                rsum[mi][j] += __shfl_xor(rsum[mi][j], m);
    if (lr == 0) {
        #pragma unroll
        for (int mi = 0; mi < 4; ++mi)
            #pragma unroll
            for (int j = 0; j < 4; ++j)
                psum[wave][mi * 16 + lg * 4 + j] = rsum[mi][j];
    }
    __syncthreads();
    if (tid < 64) {
        float n2 = psum[0][tid] + psum[1][tid] + psum[2][tid] + psum[3][tid];
        sinv[tid] = 1.f / fmaxf(sqrtf(n2), 1e-12f);
    }
    __syncthreads();

    // coalesced readback + store: 8 cols (16B bf16 / 32B f32) per thread-task
    constexpr int GPR  = DOUT / 8;           // col groups per row
    constexpr int ITER = 64 * GPR / 256;     // 4 (DOUT=128) or 2 (DOUT=64)
    #pragma unroll
    for (int i = 0; i < ITER; ++i) {
        int lin = i * 256 + tid;
        int row = lin / GPR, g = lin % GPR;
        int t = t0 + row;
        if (t < T) {
            float inv = sinv[row];
            float4 z0 = *(float4*)&smF[row * FSTR + g * 8];
            float4 z1 = *(float4*)&smF[row * FSTR + g * 8 + 4];
            float o0 = z0.x * inv, o1 = z0.y * inv, o2 = z0.z * inv, o3 = z0.w * inv;
            float o4 = z1.x * inv, o5 = z1.y * inv, o6 = z1.z * inv, o7 = z1.w * inv;
            short8 ob = {(short)f2bf(o0), (short)f2bf(o1), (short)f2bf(o2), (short)f2bf(o3),
                         (short)f2bf(o4), (short)f2bf(o5), (short)f2bf(o6), (short)f2bf(o7)};
            *(short8*)&outb[(size_t)t * DOUT + g * 8] = ob;
            if (WRITE_F32) {
                *(float4*)&outf[(size_t)t * DOUT + g * 8]     = (float4){o0, o1, o2, o3};
                *(float4*)&outf[(size_t)t * DOUT + g * 8 + 4] = (float4){o4, o5, o6, o7};
            }
        }
    }
}

// ---------------- cosine scores (bf16 embedding gathers) ----------------
// 8 lanes per pair (8 x ushort8 = 64 dims, 16B/lane)
__global__ __launch_bounds__(256) void score_kernel(const u16* __restrict__ hu,
                                                    const u16* __restrict__ hi,
                                                    const int* __restrict__ pu,
                                                    const int* __restrict__ pi,
                                                    float* __restrict__ out, int P) {
    int g = threadIdx.x >> 3, l = threadIdx.x & 7;
    int p = blockIdx.x * 32 + g;
    if (p >= P) return;
    int u = pu[p], it = pi[p];
    short8 a = *(const short8*)&hu[(size_t)u * 64 + (l << 3)];
    short8 b = *(const short8*)&hi[(size_t)it * 64 + (l << 3)];
    float d = 0.f, na = 0.f, nb = 0.f;
    #pragma unroll
    for (int q = 0; q < 8; ++q) {
        float x = bf2f((u16)a[q]), y = bf2f((u16)b[q]);
        d  = fmaf(x, y, d);
        na = fmaf(x, x, na);
        nb = fmaf(y, y, nb);
    }
    #pragma unroll
    for (int m = 1; m < 8; m <<= 1) {
        d  += __shfl_xor(d, m);
        na += __shfl_xor(na, m);
        nb += __shfl_xor(nb, m);
    }
    if (l == 0) out[p] = d / (fmaxf(sqrtf(na), 1e-12f) * fmaxf(sqrtf(nb), 1e-12f));
}

// ---------------- host ----------------

extern "C" void kernel_launch(void* const* d_in, const int* in_sizes, int n_in,
                              void* d_out, int out_size, void* d_ws, size_t ws_size,
                              hipStream_t stream) {
    const float* h_user = (const float*)d_in[0];
    const float* h_item = (const float*)d_in[1];
    const float* Wn01   = (const float*)d_in[2];
    const float* bn01   = (const float*)d_in[3];
    const float* Ws01   = (const float*)d_in[4];
    const float* bs01   = (const float*)d_in[5];
    const float* Wn2    = (const float*)d_in[6];
    const float* bn2    = (const float*)d_in[7];
    const float* Ws2    = (const float*)d_in[8];
    const float* bs2    = (const float*)d_in[9];
    const int* u2i_src  = (const int*)d_in[10];
    const int* u2i_dst  = (const int*)d_in[11];
    const int* i2u_src  = (const int*)d_in[12];
    const int* i2u_dst  = (const int*)d_in[13];
    const int* pos_u    = (const int*)d_in[14];
    const int* pos_i    = (const int*)d_in[15];
    const int* neg_u    = (const int*)d_in[16];
    const int* neg_i    = (const int*)d_in[17];

    float* out = (float*)d_out;
    float* out_hu = out;                       // [NU,64]
    float* out_hi = out + (size_t)NU * 64;     // [NI,64]
    float* out_pos = out + (size_t)NU * 64 + (size_t)NI * 64;
    float* out_neg = out_pos + NP;

    // workspace layout
    char* ws = (char*)d_ws;
    size_t off = 0;
    auto alloc = [&](size_t bytes) -> void* {
        void* p = ws + off;
        off = (off + bytes + 255) & ~(size_t)255;
        return p;
    };
    u16* hu0b = (u16*)alloc((size_t)NU * 128 * 2);   // bf16 copies of inputs
    u16* hi0b = (u16*)alloc((size_t)NI * 128 * 2);
    u16* hu_b = (u16*)alloc((size_t)NU * 128 * 2);   // layer intermediates (bf16)
    u16* hi_b = (u16*)alloc((size_t)NI * 128 * 2);
    u16* hu_a = (u16*)alloc((size_t)NU * 128 * 2);
    u16* hi_a = (u16*)alloc((size_t)NI * 128 * 2);
    u16* hu2b = (u16*)alloc((size_t)NU * 64 * 2);    // final embeddings (bf16, scores)
    u16* hi2b = (u16*)alloc((size_t)NI * 64 * 2);
    u16* wt_l0_i = (u16*)alloc((size_t)128 * 256 * 2);  // transposed bf16 weights
    u16* wt_l0_u = (u16*)alloc((size_t)128 * 256 * 2);
    u16* wt_l1_i = (u16*)alloc((size_t)128 * 256 * 2);
    u16* wt_l1_u = (u16*)alloc((size_t)128 * 256 * 2);
    u16* wt_l2_i = (u16*)alloc((size_t)64 * 256 * 2);
    u16* wt_l2_u = (u16*)alloc((size_t)64 * 256 * 2);
    int* csr_u2i = (int*)alloc((size_t)NE * 4);
    int* csr_i2u = (int*)alloc((size_t)NE * 4);
    int* rs_i   = (int*)alloc((size_t)(NI + 1) * 4);
    int* rs_u   = (int*)alloc((size_t)(NU + 1) * 4);
    int* deg    = (int*)alloc((size_t)NU * 4);
    int* cursor = (int*)alloc((size_t)NU * 4);
    int* bsum   = (int*)alloc(1024 * 4);
    (void)ws_size; (void)in_sizes; (void)n_in; (void)out_size;

    const int eblocks = (NE + 255) / 256;

    // ---- bf16 copies of input features + transposed bf16 weights ----
    cvt_kernel<<<(NU * 128 / 8 + 255) / 256, 256, 0, stream>>>(h_user, hu0b, NU * 128 / 8);
    cvt_kernel<<<(NI * 128 / 8 + 255) / 256, 256, 0, stream>>>(h_item, hi0b, NI * 128 / 8);
    wtrans_kernel<<<128, 128, 0, stream>>>(Wn01 + 0,     Ws01 + 0,     wt_l0_i, 128);
    wtrans_kernel<<<128, 128, 0, stream>>>(Wn01 + 16384, Ws01 + 16384, wt_l0_u, 128);
    wtrans_kernel<<<128, 128, 0, stream>>>(Wn01 + 32768, Ws01 + 32768, wt_l1_i, 128);
    wtrans_kernel<<<128, 128, 0, stream>>>(Wn01 + 49152, Ws01 + 49152, wt_l1_u, 128);
    wtrans_kernel<<<64, 128, 0, stream>>>(Wn2 + 0,    Ws2 + 0,    wt_l2_i, 64);
    wtrans_kernel<<<64, 128, 0, stream>>>(Wn2 + 8192, Ws2 + 8192, wt_l2_u, 64);

    // ---- CSR for u2i (dst = items) ----
    {
        hipMemsetAsync(deg, 0, (size_t)NI * 4, stream);
        hist_kernel<<<eblocks, 256, 0, stream>>>(u2i_dst, deg, NE);
        int nb = (NI + 1023) / 1024;
        scan_local_kernel<<<nb, 1024, 0, stream>>>(deg, rs_i, bsum, NI);
        scan_bsum_kernel<<<1, 1024, 0, stream>>>(bsum, nb);
        scan_finalize_kernel<<<nb, 1024, 0, stream>>>(rs_i, bsum, cursor, NI, NE);
        fill_kernel<<<eblocks * 8, 256, 0, stream>>>(u2i_src, u2i_dst, cursor,
                                                     csr_u2i, NE, NI);
    }
    // ---- CSR for i2u (dst = users) ----
    {
        hipMemsetAsync(deg, 0, (size_t)NU * 4, stream);
        hist_kernel<<<eblocks, 256, 0, stream>>>(i2u_dst, deg, NE);
        int nb = (NU + 1023) / 1024;
        scan_local_kernel<<<nb, 1024, 0, stream>>>(deg, rs_u, bsum, NU);
        scan_bsum_kernel<<<1, 1024, 0, stream>>>(bsum, nb);
        scan_finalize_kernel<<<nb, 1024, 0, stream>>>(rs_u, bsum, cursor, NU, NE);
        fill_kernel<<<eblocks * 8, 256, 0, stream>>>(i2u_src, i2u_dst, cursor,
                                                     csr_i2u, NE, NU);
    }

    const int ci = (NI + 63) / 64, cu = (NU + 63) / 64;      // fused grids (64-row tiles)

    // ---- layer 0 ----
    fused_conv_kernel<128, false><<<ci, 256, 0, stream>>>(hu0b, hi0b, rs_i, csr_u2i,
                                                          wt_l0_i, bn01 + 0, bs01 + 0,
                                                          nullptr, hi_b, NI);
    fused_conv_kernel<128, false><<<cu, 256, 0, stream>>>(hi0b, hu0b, rs_u, csr_i2u,
                                                          wt_l0_u, bn01 + 128, bs01 + 128,
                                                          nullptr, hu_b, NU);
    // ---- layer 1 ----
    fused_conv_kernel<128, false><<<ci, 256, 0, stream>>>(hu_b, hi_b, rs_i, csr_u2i,
                                                          wt_l1_i, bn01 + 256, bs01 + 256,
                                                          nullptr, hi_a, NI);
    fused_conv_kernel<128, false><<<cu, 256, 0, stream>>>(hi_b, hu_b, rs_u, csr_i2u,
                                                          wt_l1_u, bn01 + 384, bs01 + 384,
                                                          nullptr, hu_a, NU);
    // ---- layer 2 (writes d_out embeddings f32 + bf16 copy for scores) ----
    fused_conv_kernel<64, true><<<ci, 256, 0, stream>>>(hu_a, hi_a, rs_i, csr_u2i,
                                                        wt_l2_i, bn2 + 0, bs2 + 0,
                                                        out_hi, hi2b, NI);
    fused_conv_kernel<64, true><<<cu, 256, 0, stream>>>(hi_a, hu_a, rs_u, csr_i2u,
                                                        wt_l2_u, bn2 + 64, bs2 + 64,
                                                        out_hu, hu2b, NU);

    // ---- cosine scores ----
    const int pblocks = (NP + 31) / 32;
    score_kernel<<<pblocks, 256, 0, stream>>>(hu2b, hi2b, pos_u, pos_i, out_pos, NP);
    score_kernel<<<pblocks, 256, 0, stream>>>(hu2b, hi2b, neg_u, neg_i, out_neg, NP);
}

// Round 11
// 611.979 us; speedup vs baseline: 1.1748x; 1.1748x over previous
//
#include <hip/hip_runtime.h>
#include <hip/hip_bf16.h>

// Problem constants (from reference)
#define NU 100000
#define NI 50000
#define NE 1000000
#define NP 500000
// D_IN = D_HID = 128, D_OUT = 64

typedef unsigned short u16;
typedef unsigned int u32;
typedef __attribute__((ext_vector_type(8))) short short8;   // 8 bf16 (4 VGPRs)
typedef __attribute__((ext_vector_type(4))) float f32x4;

static __device__ __forceinline__ u16 f2bf(float f) {
    union { float f; u32 u; } x; x.f = f;
    u32 r = x.u + 0x7fff + ((x.u >> 16) & 1);   // round-to-nearest-even
    return (u16)(r >> 16);
}
static __device__ __forceinline__ float bf2f(u16 h) {
    union { u32 u; float f; } x; x.u = ((u32)h) << 16;
    return x.f;
}

// ---------------- f32 -> bf16 table conversion ----------------
__global__ __launch_bounds__(256) void cvt_kernel(const float* __restrict__ in,
                                                  u16* __restrict__ out, int n8) {
    int i = blockIdx.x * blockDim.x + threadIdx.x;
    if (i >= n8) return;
    float4 a = ((const float4*)in)[2 * i];
    float4 b = ((const float4*)in)[2 * i + 1];
    ushort4 lo = {f2bf(a.x), f2bf(a.y), f2bf(a.z), f2bf(a.w)};
    ushort4 hi = {f2bf(b.x), f2bf(b.y), f2bf(b.z), f2bf(b.w)};
    ((ushort4*)out)[2 * i]     = lo;
    ((ushort4*)out)[2 * i + 1] = hi;
}

// ---------------- all 6 weight transposes in one launch ----------------
// wt layout (u16, contiguous): 4 x (128x256) for layers 0/1, then 2 x (64x256).
__global__ void wtrans_all_kernel(const float* __restrict__ Wn01,
                                  const float* __restrict__ Ws01,
                                  const float* __restrict__ Wn2,
                                  const float* __restrict__ Ws2,
                                  u16* __restrict__ wt) {
    int x = blockIdx.x;            // 0..639
    int k = threadIdx.x;           // 0..127
    const float *Wn, *Ws; int n, N; size_t off_out;
    if (x < 512) {
        int m = x >> 7; n = x & 127; N = 128;
        Wn = Wn01 + m * 16384; Ws = Ws01 + m * 16384;
        off_out = (size_t)m * 128 * 256;
    } else {
        int m = (x - 512) >> 6; n = (x - 512) & 63; N = 64;
        Wn = Wn2 + m * 8192; Ws = Ws2 + m * 8192;
        off_out = (size_t)4 * 128 * 256 + (size_t)m * 64 * 256;
    }
    wt[off_out + (size_t)n * 256 + k]       = f2bf(Wn[(size_t)k * N + n]);
    wt[off_out + (size_t)n * 256 + 128 + k] = f2bf(Ws[(size_t)k * N + n]);
}

// ---------------- CSR build ----------------

// both histograms in one launch (y = direction)
__global__ void hist2_kernel(const int* __restrict__ d0, int* __restrict__ deg0,
                             const int* __restrict__ d1, int* __restrict__ deg1, int E) {
    int e = blockIdx.x * blockDim.x + threadIdx.x;
    if (e >= E) return;
    if (blockIdx.y == 0) atomicAdd(&deg0[__builtin_nontemporal_load(&d0[e])], 1);
    else                 atomicAdd(&deg1[__builtin_nontemporal_load(&d1[e])], 1);
}

__global__ void scan_local_kernel(const int* __restrict__ in, int* __restrict__ out,
                                  int* __restrict__ bsum, int n) {
    __shared__ int s[1024];
    int i = blockIdx.x * 1024 + threadIdx.x;
    int v = (i < n) ? in[i] : 0;
    s[threadIdx.x] = v;
    __syncthreads();
    for (int off = 1; off < 1024; off <<= 1) {
        int t = (threadIdx.x >= off) ? s[threadIdx.x - off] : 0;
        __syncthreads();
        s[threadIdx.x] += t;
        __syncthreads();
    }
    if (i < n) out[i] = s[threadIdx.x] - v;   // exclusive within block
    if (threadIdx.x == 1023) bsum[blockIdx.x] = s[1023];
}

__global__ void scan_bsum_kernel(int* bsum, int nb) {
    __shared__ int s[1024];
    int v = (threadIdx.x < nb) ? bsum[threadIdx.x] : 0;
    s[threadIdx.x] = v;
    __syncthreads();
    for (int off = 1; off < 1024; off <<= 1) {
        int t = (threadIdx.x >= off) ? s[threadIdx.x - off] : 0;
        __syncthreads();
        s[threadIdx.x] += t;
        __syncthreads();
    }
    if (threadIdx.x < nb) bsum[threadIdx.x] = s[threadIdx.x] - v;  // exclusive
}

__global__ void scan_finalize_kernel(int* __restrict__ rs, const int* __restrict__ bsum,
                                     int* __restrict__ cursor, int n, int E) {
    int i = blockIdx.x * 1024 + threadIdx.x;
    if (i < n) {
        int v = rs[i] + bsum[blockIdx.x];
        rs[i] = v;
        cursor[i] = v;
    }
    if (i == 0) rs[n] = E;
}

// XCD-aligned dst-partitioned fill, BOTH directions in one launch (y).
// window = blockIdx.x & 7 pins each csr window to one XCD's L2 (dispatch
// round-robins x over XCDs); edge-stream reads NON-TEMPORAL so the 8 re-read
// passes don't evict partially-filled dirty csr lines.
__global__ void fill2_kernel(const int* __restrict__ s0, const int* __restrict__ d0,
                             int* cur0, int* __restrict__ csr0, int n0,
                             const int* __restrict__ s1, const int* __restrict__ d1,
                             int* cur1, int* __restrict__ csr1, int n1, int E) {
    const int *src, *dst; int *cursor, *csr; int n;
    if (blockIdx.y == 0) { src = s0; dst = d0; cursor = cur0; csr = csr0; n = n0; }
    else                 { src = s1; dst = d1; cursor = cur1; csr = csr1; n = n1; }
    int window = blockIdx.x & 7;
    int e = (blockIdx.x >> 3) * blockDim.x + threadIdx.x;
    if (e >= E) return;
    int d = __builtin_nontemporal_load(&dst[e]);
    int chunk = (n + 7) >> 3;
    int lo = window * chunk;
    if (d >= lo && d < lo + chunk) {
        int p = atomicAdd(&cursor[d], 1);
        csr[p] = __builtin_nontemporal_load(&src[e]);
    }
}

// ---------------- mean aggregation, items + users in ONE launch ----------------
// 4 dst nodes per 256-thread block; one wave per node (max TLP: no LDS, low
// VGPR -> ~8 waves/SIMD; fusion into conv was tried in r10 and REGRESSED:
// gather is latency-bound and needs this occupancy).
// 16 lanes per edge-row (ushort8 = 16B), 4 edge slots, 16 loads in flight.
// csr loads NON-TEMPORAL (stream, don't evict feature rows from L2);
// output stores NON-TEMPORAL (pure stream, consumed by next kernel).
__global__ __launch_bounds__(256) void agg2_kernel(
    const u16* __restrict__ hu, const u16* __restrict__ hi,
    const int* __restrict__ rs_i, const int* __restrict__ csr_i,
    u16* __restrict__ out_i, int gi,
    const int* __restrict__ rs_u, const int* __restrict__ csr_u,
    u16* __restrict__ out_u) {
    const u16* hsrc; const int *rs, *csr; u16* out; int T, t;
    int bx = blockIdx.x;
    if (bx < gi) { hsrc = hu; rs = rs_i; csr = csr_i; out = out_i; T = NI;
                   t = bx * 4 + (threadIdx.x >> 6); }
    else         { hsrc = hi; rs = rs_u; csr = csr_u; out = out_u; T = NU;
                   t = (bx - gi) * 4 + (threadIdx.x >> 6); }
    if (t >= T) return;
    const int lane = threadIdx.x & 63;
    const int lr   = lane & 15;        // dims lr*8 .. lr*8+7
    const int sub  = lane >> 4;        // edge slot 0..3
    int e0 = rs[t], e1 = rs[t + 1];
    float acc[8] = {};
    int e = e0 + sub;
    for (; e + 12 < e1; e += 16) {     // 4 rows in flight per slot
        int s0 = __builtin_nontemporal_load(&csr[e]);
        int s1 = __builtin_nontemporal_load(&csr[e + 4]);
        int s2 = __builtin_nontemporal_load(&csr[e + 8]);
        int s3 = __builtin_nontemporal_load(&csr[e + 12]);
        short8 v0 = *(const short8*)&hsrc[(size_t)s0 * 128 + (lr << 3)];
        short8 v1 = *(const short8*)&hsrc[(size_t)s1 * 128 + (lr << 3)];
        short8 v2 = *(const short8*)&hsrc[(size_t)s2 * 128 + (lr << 3)];
        short8 v3 = *(const short8*)&hsrc[(size_t)s3 * 128 + (lr << 3)];
        #pragma unroll
        for (int q = 0; q < 8; ++q)
            acc[q] += (bf2f((u16)v0[q]) + bf2f((u16)v1[q])) +
                      (bf2f((u16)v2[q]) + bf2f((u16)v3[q]));
    }
    for (; e + 4 < e1; e += 8) {
        int s0 = __builtin_nontemporal_load(&csr[e]);
        int s1 = __builtin_nontemporal_load(&csr[e + 4]);
        short8 v0 = *(const short8*)&hsrc[(size_t)s0 * 128 + (lr << 3)];
        short8 v1 = *(const short8*)&hsrc[(size_t)s1 * 128 + (lr << 3)];
        #pragma unroll
        for (int q = 0; q < 8; ++q)
            acc[q] += bf2f((u16)v0[q]) + bf2f((u16)v1[q]);
    }
    if (e < e1) {
        int s0 = __builtin_nontemporal_load(&csr[e]);
        short8 v0 = *(const short8*)&hsrc[(size_t)s0 * 128 + (lr << 3)];
        #pragma unroll
        for (int q = 0; q < 8; ++q) acc[q] += bf2f((u16)v0[q]);
    }
    // reduce across the 4 edge slots (lanes differing in bits 4,5)
    #pragma unroll
    for (int q = 0; q < 8; ++q) {
        acc[q] += __shfl_xor(acc[q], 16);
        acc[q] += __shfl_xor(acc[q], 32);
    }
    if (sub == 0) {
        float inv = (e1 > e0) ? 1.f / (float)(e1 - e0) : 0.f;
        short8 o;
        #pragma unroll
        for (int q = 0; q < 8; ++q) o[q] = (short)f2bf(acc[q] * inv);
        __builtin_nontemporal_store(o, (short8*)&out[(size_t)t * 128 + (lr << 3)]);
    }
}

// ---------------- conv via MFMA, items + users in ONE launch ----------------
// z = [hn|hd] @ Wt^T + bn + bs; relu; row L2-norm.
// Block = 256 threads = 4 waves, 64-row tile. A staged once in LDS (coalesced
// 16B loads, 264-u16 stride). Wave w owns cols [w*16*NF,...), 4 row-frags.
// Epilogue transposes normalized output through LDS -> coalesced 16B stores.
template <int DOUT, bool WRITE_F32>
__global__ __launch_bounds__(256) void conv2_kernel(
    const u16* __restrict__ hn_i, const u16* __restrict__ hd_i,
    const u16* __restrict__ wt_i, const float* __restrict__ bn_i,
    const float* __restrict__ bs_i, float* __restrict__ outf_i,
    u16* __restrict__ outb_i, int ci,
    const u16* __restrict__ hn_u, const u16* __restrict__ hd_u,
    const u16* __restrict__ wt_u, const float* __restrict__ bn_u,
    const float* __restrict__ bs_u, float* __restrict__ outf_u,
    u16* __restrict__ outb_u)
{
    constexpr int NF   = DOUT / 64;               // col fragments per wave (2 or 1)
    constexpr int FSTR = (DOUT == 128) ? 132 : 68; // f32 out stride (16B-aligned rows)
    __shared__ u16 smA[64 * 264];                  // 33792 B, reused as f32 out
    __shared__ float psum[4][64];
    __shared__ float sinv[64];
    float* smF = (float*)smA;

    const u16 *hn, *hd, *Wt; const float *bn, *bs; float* outf; u16* outb; int T, t0;
    if ((int)blockIdx.x < ci) {
        hn = hn_i; hd = hd_i; Wt = wt_i; bn = bn_i; bs = bs_i;
        outf = outf_i; outb = outb_i; T = NI; t0 = blockIdx.x * 64;
    } else {
        hn = hn_u; hd = hd_u; Wt = wt_u; bn = bn_u; bs = bs_u;
        outf = outf_u; outb = outb_u; T = NU; t0 = (blockIdx.x - ci) * 64;
    }

    const int tid  = threadIdx.x;
    const int wave = tid >> 6;
    const int lane = tid & 63;
    const int lr   = lane & 15;
    const int lg   = lane >> 4;                    // 0..3

    // ---- stage A = [hn | hd]: 64 rows x 256 u16, 16B per thread-chunk ----
    #pragma unroll
    for (int i = 0; i < 8; ++i) {
        int lin = i * 256 + tid;                   // 0..2047
        int row = lin >> 5;
        int q   = lin & 31;                        // 16B chunk within row
        int t   = t0 + row; if (t >= T) t = T - 1; // clamp; stores guarded
        const u16* srcp = (q < 16) ? &hn[(size_t)t * 128 + (q << 3)]
                                   : &hd[(size_t)t * 128 + ((q - 16) << 3)];
        *(short8*)&smA[row * 264 + (q << 3)] = *(const short8*)srcp;
    }
    __syncthreads();

    const u16* wp[NF];
    float bias[NF];
    #pragma unroll
    for (int ni = 0; ni < NF; ++ni) {
        int col = wave * (16 * NF) + ni * 16 + lr;
        wp[ni] = Wt + (size_t)col * 256;
        bias[ni] = bn[col] + bs[col];
    }

    f32x4 acc[4][NF];
    #pragma unroll
    for (int mi = 0; mi < 4; ++mi)
        #pragma unroll
        for (int ni = 0; ni < NF; ++ni)
            acc[mi][ni] = (f32x4){0.f, 0.f, 0.f, 0.f};

    #pragma unroll
    for (int ks = 0; ks < 8; ++ks) {
        const int kb = ks * 32 + (lg << 3);
        short8 b[NF];
        #pragma unroll
        for (int ni = 0; ni < NF; ++ni) b[ni] = *(const short8*)&wp[ni][kb];
        #pragma unroll
        for (int mi = 0; mi < 4; ++mi) {
            short8 a = *(const short8*)&smA[(mi * 16 + lr) * 264 + kb];
            #pragma unroll
            for (int ni = 0; ni < NF; ++ni)
                acc[mi][ni] = __builtin_amdgcn_mfma_f32_16x16x32_bf16(a, b[ni], acc[mi][ni], 0, 0, 0);
        }
    }
    __syncthreads();   // all waves done reading smA before overwrite as f32

    // bias + relu; z -> LDS (transpose buffer); per-row partial square-sums
    float rsum[4][4];
    #pragma unroll
    for (int mi = 0; mi < 4; ++mi) {
        #pragma unroll
        for (int j = 0; j < 4; ++j) {
            int rowg = mi * 16 + lg * 4 + j;
            float s = 0.f;
            #pragma unroll
            for (int ni = 0; ni < NF; ++ni) {
                float z = fmaxf(acc[mi][ni][j] + bias[ni], 0.f);
                int colg = wave * (16 * NF) + ni * 16 + lr;
                smF[rowg * FSTR + colg] = z;
                s = fmaf(z, z, s);
            }
            rsum[mi][j] = s;
        }
    }
    #pragma unroll
    for (int m = 1; m < 16; m <<= 1)
        #pragma unroll
        for (int mi = 0; mi < 4; ++mi)
            #pragma unroll
            for (int j = 0; j < 4; ++j)
                rsum[mi][j] += __shfl_xor(rsum[mi][j], m);
    if (lr == 0) {
        #pragma unroll
        for (int mi = 0; mi < 4; ++mi)
            #pragma unroll
            for (int j = 0; j < 4; ++j)
                psum[wave][mi * 16 + lg * 4 + j] = rsum[mi][j];
    }
    __syncthreads();
    if (tid < 64) {
        float n2 = psum[0][tid] + psum[1][tid] + psum[2][tid] + psum[3][tid];
        sinv[tid] = 1.f / fmaxf(sqrtf(n2), 1e-12f);
    }
    __syncthreads();

    // coalesced readback + store: 8 cols (16B bf16 / 32B f32) per thread-task
    constexpr int GPR  = DOUT / 8;           // col groups per row
    constexpr int ITER = 64 * GPR / 256;     // 4 (DOUT=128) or 2 (DOUT=64)
    #pragma unroll
    for (int i = 0; i < ITER; ++i) {
        int lin = i * 256 + tid;
        int row = lin / GPR, g = lin % GPR;
        int t = t0 + row;
        if (t < T) {
            float inv = sinv[row];
            float4 z0 = *(float4*)&smF[row * FSTR + g * 8];
            float4 z1 = *(float4*)&smF[row * FSTR + g * 8 + 4];
            float o0 = z0.x * inv, o1 = z0.y * inv, o2 = z0.z * inv, o3 = z0.w * inv;
            float o4 = z1.x * inv, o5 = z1.y * inv, o6 = z1.z * inv, o7 = z1.w * inv;
            short8 ob = {(short)f2bf(o0), (short)f2bf(o1), (short)f2bf(o2), (short)f2bf(o3),
                         (short)f2bf(o4), (short)f2bf(o5), (short)f2bf(o6), (short)f2bf(o7)};
            *(short8*)&outb[(size_t)t * DOUT + g * 8] = ob;
            if (WRITE_F32) {
                *(float4*)&outf[(size_t)t * DOUT + g * 8]     = (float4){o0, o1, o2, o3};
                *(float4*)&outf[(size_t)t * DOUT + g * 8 + 4] = (float4){o4, o5, o6, o7};
            }
        }
    }
}

// ---------------- cosine scores, pos + neg in ONE launch ----------------
// 8 lanes per pair (8 x ushort8 = 64 dims, 16B/lane); y = pos/neg.
__global__ __launch_bounds__(256) void score2_kernel(
    const u16* __restrict__ hu, const u16* __restrict__ hi,
    const int* __restrict__ pu0, const int* __restrict__ pi0, float* __restrict__ out0,
    const int* __restrict__ pu1, const int* __restrict__ pi1, float* __restrict__ out1,
    int P) {
    const int *pu, *pi; float* out;
    if (blockIdx.y == 0) { pu = pu0; pi = pi0; out = out0; }
    else                 { pu = pu1; pi = pi1; out = out1; }
    int g = threadIdx.x >> 3, l = threadIdx.x & 7;
    int p = blockIdx.x * 32 + g;
    if (p >= P) return;
    int u = __builtin_nontemporal_load(&pu[p]);
    int it = __builtin_nontemporal_load(&pi[p]);
    short8 a = *(const short8*)&hu[(size_t)u * 64 + (l << 3)];
    short8 b = *(const short8*)&hi[(size_t)it * 64 + (l << 3)];
    float d = 0.f, na = 0.f, nb = 0.f;
    #pragma unroll
    for (int q = 0; q < 8; ++q) {
        float x = bf2f((u16)a[q]), y = bf2f((u16)b[q]);
        d  = fmaf(x, y, d);
        na = fmaf(x, x, na);
        nb = fmaf(y, y, nb);
    }
    #pragma unroll
    for (int m = 1; m < 8; m <<= 1) {
        d  += __shfl_xor(d, m);
        na += __shfl_xor(na, m);
        nb += __shfl_xor(nb, m);
    }
    if (l == 0) out[p] = d / (fmaxf(sqrtf(na), 1e-12f) * fmaxf(sqrtf(nb), 1e-12f));
}

// ---------------- host ----------------

extern "C" void kernel_launch(void* const* d_in, const int* in_sizes, int n_in,
                              void* d_out, int out_size, void* d_ws, size_t ws_size,
                              hipStream_t stream) {
    const float* h_user = (const float*)d_in[0];
    const float* h_item = (const float*)d_in[1];
    const float* Wn01   = (const float*)d_in[2];
    const float* bn01   = (const float*)d_in[3];
    const float* Ws01   = (const float*)d_in[4];
    const float* bs01   = (const float*)d_in[5];
    const float* Wn2    = (const float*)d_in[6];
    const float* bn2    = (const float*)d_in[7];
    const float* Ws2    = (const float*)d_in[8];
    const float* bs2    = (const float*)d_in[9];
    const int* u2i_src  = (const int*)d_in[10];
    const int* u2i_dst  = (const int*)d_in[11];
    const int* i2u_src  = (const int*)d_in[12];
    const int* i2u_dst  = (const int*)d_in[13];
    const int* pos_u    = (const int*)d_in[14];
    const int* pos_i    = (const int*)d_in[15];
    const int* neg_u    = (const int*)d_in[16];
    const int* neg_i    = (const int*)d_in[17];

    float* out = (float*)d_out;
    float* out_hu = out;                       // [NU,64]
    float* out_hi = out + (size_t)NU * 64;     // [NI,64]
    float* out_pos = out + (size_t)NU * 64 + (size_t)NI * 64;
    float* out_neg = out_pos + NP;

    // workspace layout
    char* ws = (char*)d_ws;
    size_t off = 0;
    auto alloc = [&](size_t bytes) -> void* {
        void* p = ws + off;
        off = (off + bytes + 255) & ~(size_t)255;
        return p;
    };
    u16* hu0b = (u16*)alloc((size_t)NU * 128 * 2);   // bf16 copies of inputs
    u16* hi0b = (u16*)alloc((size_t)NI * 128 * 2);
    u16* hu_b = (u16*)alloc((size_t)NU * 128 * 2);   // layer intermediates (bf16)
    u16* hi_b = (u16*)alloc((size_t)NI * 128 * 2);
    u16* hu_a = (u16*)alloc((size_t)NU * 128 * 2);
    u16* hi_a = (u16*)alloc((size_t)NI * 128 * 2);
    u16* agg_i = (u16*)alloc((size_t)NI * 128 * 2);  // agg outputs (bf16)
    u16* agg_u = (u16*)alloc((size_t)NU * 128 * 2);
    u16* hu2b = (u16*)alloc((size_t)NU * 64 * 2);    // final embeddings (bf16, scores)
    u16* hi2b = (u16*)alloc((size_t)NI * 64 * 2);
    u16* wt_all = (u16*)alloc((size_t)(4 * 128 * 256 + 2 * 64 * 256) * 2);
    u16* wt_l0_i = wt_all;                 // each 128x256
    u16* wt_l0_u = wt_all + 32768;
    u16* wt_l1_i = wt_all + 65536;
    u16* wt_l1_u = wt_all + 98304;
    u16* wt_l2_i = wt_all + 131072;        // 64x256
    u16* wt_l2_u = wt_all + 147456;
    int* csr_u2i = (int*)alloc((size_t)NE * 4);
    int* csr_i2u = (int*)alloc((size_t)NE * 4);
    int* rs_i   = (int*)alloc((size_t)(NI + 1) * 4);
    int* rs_u   = (int*)alloc((size_t)(NU + 1) * 4);
    int* deg    = (int*)alloc((size_t)(NI + NU) * 4);   // deg_i | deg_u
    int* cursor = (int*)alloc((size_t)(NI + NU) * 4);   // cursor_i | cursor_u
    int* bsum   = (int*)alloc(1024 * 4);
    int* deg_i = deg, *deg_u = deg + NI;
    int* cur_i = cursor, *cur_u = cursor + NI;
    (void)ws_size; (void)in_sizes; (void)n_in; (void)out_size;

    const int eblocks = (NE + 255) / 256;

    // ---- bf16 copies of input features + all transposed bf16 weights ----
    cvt_kernel<<<(NU * 128 / 8 + 255) / 256, 256, 0, stream>>>(h_user, hu0b, NU * 128 / 8);
    cvt_kernel<<<(NI * 128 / 8 + 255) / 256, 256, 0, stream>>>(h_item, hi0b, NI * 128 / 8);
    wtrans_all_kernel<<<640, 128, 0, stream>>>(Wn01, Ws01, Wn2, Ws2, wt_all);

    // ---- CSR build (both directions) ----
    hipMemsetAsync(deg, 0, (size_t)(NI + NU) * 4, stream);
    hist2_kernel<<<dim3(eblocks, 2), 256, 0, stream>>>(u2i_dst, deg_i, i2u_dst, deg_u, NE);
    {
        int nb = (NI + 1023) / 1024;
        scan_local_kernel<<<nb, 1024, 0, stream>>>(deg_i, rs_i, bsum, NI);
        scan_bsum_kernel<<<1, 1024, 0, stream>>>(bsum, nb);
        scan_finalize_kernel<<<nb, 1024, 0, stream>>>(rs_i, bsum, cur_i, NI, NE);
    }
    {
        int nb = (NU + 1023) / 1024;
        scan_local_kernel<<<nb, 1024, 0, stream>>>(deg_u, rs_u, bsum, NU);
        scan_bsum_kernel<<<1, 1024, 0, stream>>>(bsum, nb);
        scan_finalize_kernel<<<nb, 1024, 0, stream>>>(rs_u, bsum, cur_u, NU, NE);
    }
    fill2_kernel<<<dim3(eblocks * 8, 2), 256, 0, stream>>>(
        u2i_src, u2i_dst, cur_i, csr_u2i, NI,
        i2u_src, i2u_dst, cur_u, csr_i2u, NU, NE);

    const int gi = (NI + 3) / 4, gu = (NU + 3) / 4;          // agg sub-grids
    const int ci = (NI + 63) / 64, cu = (NU + 63) / 64;      // conv sub-grids

    // ---- layer 0 ----
    agg2_kernel<<<gi + gu, 256, 0, stream>>>(hu0b, hi0b, rs_i, csr_u2i, agg_i, gi,
                                             rs_u, csr_i2u, agg_u);
    conv2_kernel<128, false><<<ci + cu, 256, 0, stream>>>(
        agg_i, hi0b, wt_l0_i, bn01 + 0, bs01 + 0, nullptr, hi_b, ci,
        agg_u, hu0b, wt_l0_u, bn01 + 128, bs01 + 128, nullptr, hu_b);
    // ---- layer 1 ----
    agg2_kernel<<<gi + gu, 256, 0, stream>>>(hu_b, hi_b, rs_i, csr_u2i, agg_i, gi,
                                             rs_u, csr_i2u, agg_u);
    conv2_kernel<128, false><<<ci + cu, 256, 0, stream>>>(
        agg_i, hi_b, wt_l1_i, bn01 + 256, bs01 + 256, nullptr, hi_a, ci,
        agg_u, hu_b, wt_l1_u, bn01 + 384, bs01 + 384, nullptr, hu_a);
    // ---- layer 2 (writes d_out embeddings f32 + bf16 copy for scores) ----
    agg2_kernel<<<gi + gu, 256, 0, stream>>>(hu_a, hi_a, rs_i, csr_u2i, agg_i, gi,
                                             rs_u, csr_i2u, agg_u);
    conv2_kernel<64, true><<<ci + cu, 256, 0, stream>>>(
        agg_i, hi_a, wt_l2_i, bn2 + 0, bs2 + 0, out_hi, hi2b, ci,
        agg_u, hu_a, wt_l2_u, bn2 + 64, bs2 + 64, out_hu, hu2b);

    // ---- cosine scores (pos + neg in one launch) ----
    score2_kernel<<<dim3((NP + 31) / 32, 2), 256, 0, stream>>>(
        hu2b, hi2b, pos_u, pos_i, out_pos, neg_u, neg_i, out_neg, NP);
}

// Round 12
// 569.287 us; speedup vs baseline: 1.2630x; 1.0750x over previous
//
#include <hip/hip_runtime.h>
#include <hip/hip_bf16.h>

// Problem constants (from reference)
#define NU 100000
#define NI 50000
#define NE 1000000
#define NP 500000
// D_IN = D_HID = 128, D_OUT = 64

typedef unsigned short u16;
typedef unsigned int u32;
typedef __attribute__((ext_vector_type(8))) short short8;   // 8 bf16 (4 VGPRs)
typedef __attribute__((ext_vector_type(4))) float f32x4;

static __device__ __forceinline__ u16 f2bf(float f) {
    union { float f; u32 u; } x; x.f = f;
    u32 r = x.u + 0x7fff + ((x.u >> 16) & 1);   // round-to-nearest-even
    return (u16)(r >> 16);
}
static __device__ __forceinline__ float bf2f(u16 h) {
    union { u32 u; float f; } x; x.u = ((u32)h) << 16;
    return x.f;
}

// ---------------- f32 -> bf16 table conversion ----------------
__global__ __launch_bounds__(256) void cvt_kernel(const float* __restrict__ in,
                                                  u16* __restrict__ out, int n8) {
    int i = blockIdx.x * blockDim.x + threadIdx.x;
    if (i >= n8) return;
    float4 a = ((const float4*)in)[2 * i];
    float4 b = ((const float4*)in)[2 * i + 1];
    ushort4 lo = {f2bf(a.x), f2bf(a.y), f2bf(a.z), f2bf(a.w)};
    ushort4 hi = {f2bf(b.x), f2bf(b.y), f2bf(b.z), f2bf(b.w)};
    ((ushort4*)out)[2 * i]     = lo;
    ((ushort4*)out)[2 * i + 1] = hi;
}

// ---------------- all 6 weight transposes in one launch ----------------
// wt layout (u16, contiguous): 4 x (128x256) for layers 0/1, then 2 x (64x256).
__global__ void wtrans_all_kernel(const float* __restrict__ Wn01,
                                  const float* __restrict__ Ws01,
                                  const float* __restrict__ Wn2,
                                  const float* __restrict__ Ws2,
                                  u16* __restrict__ wt) {
    int x = blockIdx.x;            // 0..639
    int k = threadIdx.x;           // 0..127
    const float *Wn, *Ws; int n, N; size_t off_out;
    if (x < 512) {
        int m = x >> 7; n = x & 127; N = 128;
        Wn = Wn01 + m * 16384; Ws = Ws01 + m * 16384;
        off_out = (size_t)m * 128 * 256;
    } else {
        int m = (x - 512) >> 6; n = (x - 512) & 63; N = 64;
        Wn = Wn2 + m * 8192; Ws = Ws2 + m * 8192;
        off_out = (size_t)4 * 128 * 256 + (size_t)m * 64 * 256;
    }
    wt[off_out + (size_t)n * 256 + k]       = f2bf(Wn[(size_t)k * N + n]);
    wt[off_out + (size_t)n * 256 + 128 + k] = f2bf(Ws[(size_t)k * N + n]);
}

// ---------------- CSR build ----------------

// both histograms in one launch (y = direction); ALSO captures each edge's
// rank within its dst (the atomicAdd return we already pay for) so the fill
// pass needs no atomics and no window re-reads (round-11 profile: 8-pass
// windowed fill fetched 62MB re-reading dst streams).
__global__ void hist2_kernel(const int* __restrict__ d0, int* __restrict__ deg0,
                             int* __restrict__ rank0,
                             const int* __restrict__ d1, int* __restrict__ deg1,
                             int* __restrict__ rank1, int E) {
    int e = blockIdx.x * blockDim.x + threadIdx.x;
    if (e >= E) return;
    if (blockIdx.y == 0) {
        int d = __builtin_nontemporal_load(&d0[e]);
        int r = atomicAdd(&deg0[d], 1);
        __builtin_nontemporal_store(r, &rank0[e]);
    } else {
        int d = __builtin_nontemporal_load(&d1[e]);
        int r = atomicAdd(&deg1[d], 1);
        __builtin_nontemporal_store(r, &rank1[e]);
    }
}

__global__ void scan_local_kernel(const int* __restrict__ in, int* __restrict__ out,
                                  int* __restrict__ bsum, int n) {
    __shared__ int s[1024];
    int i = blockIdx.x * 1024 + threadIdx.x;
    int v = (i < n) ? in[i] : 0;
    s[threadIdx.x] = v;
    __syncthreads();
    for (int off = 1; off < 1024; off <<= 1) {
        int t = (threadIdx.x >= off) ? s[threadIdx.x - off] : 0;
        __syncthreads();
        s[threadIdx.x] += t;
        __syncthreads();
    }
    if (i < n) out[i] = s[threadIdx.x] - v;   // exclusive within block
    if (threadIdx.x == 1023) bsum[blockIdx.x] = s[1023];
}

__global__ void scan_bsum_kernel(int* bsum, int nb) {
    __shared__ int s[1024];
    int v = (threadIdx.x < nb) ? bsum[threadIdx.x] : 0;
    s[threadIdx.x] = v;
    __syncthreads();
    for (int off = 1; off < 1024; off <<= 1) {
        int t = (threadIdx.x >= off) ? s[threadIdx.x - off] : 0;
        __syncthreads();
        s[threadIdx.x] += t;
        __syncthreads();
    }
    if (threadIdx.x < nb) bsum[threadIdx.x] = s[threadIdx.x] - v;  // exclusive
}

__global__ void scan_finalize_kernel(int* __restrict__ rs, const int* __restrict__ bsum,
                                     int n, int E) {
    int i = blockIdx.x * 1024 + threadIdx.x;
    if (i < n) rs[i] += bsum[blockIdx.x];
    if (i == 0) rs[n] = E;
}

// single-pass atomic-free fill: csr[rs[d] + rank[e]] = src[e].
// Streams are NT loads; rs gather is cached (400KB, L2/L3). Each csr slot is
// written exactly once.
__global__ void fill2_kernel(const int* __restrict__ s0, const int* __restrict__ d0,
                             const int* __restrict__ r0, const int* __restrict__ rs0,
                             int* __restrict__ csr0,
                             const int* __restrict__ s1, const int* __restrict__ d1,
                             const int* __restrict__ r1, const int* __restrict__ rs1,
                             int* __restrict__ csr1, int E) {
    const int *src, *dst, *rk, *rs; int* csr;
    if (blockIdx.y == 0) { src = s0; dst = d0; rk = r0; rs = rs0; csr = csr0; }
    else                 { src = s1; dst = d1; rk = r1; rs = rs1; csr = csr1; }
    int e = blockIdx.x * blockDim.x + threadIdx.x;
    if (e >= E) return;
    int d = __builtin_nontemporal_load(&dst[e]);
    int r = __builtin_nontemporal_load(&rk[e]);
    int s = __builtin_nontemporal_load(&src[e]);
    csr[rs[d] + r] = s;
}

// ---------------- mean aggregation, items + users in ONE launch ----------------
// 4 dst nodes per 256-thread block; one wave per node (max TLP: no LDS, low
// VGPR -> ~8 waves/SIMD; fusion into conv was tried in r10 and REGRESSED:
// gather is latency-bound and needs this occupancy).
// 16 lanes per edge-row (ushort8 = 16B), 4 edge slots, 16 loads in flight.
__global__ __launch_bounds__(256) void agg2_kernel(
    const u16* __restrict__ hu, const u16* __restrict__ hi,
    const int* __restrict__ rs_i, const int* __restrict__ csr_i,
    u16* __restrict__ out_i, int gi,
    const int* __restrict__ rs_u, const int* __restrict__ csr_u,
    u16* __restrict__ out_u) {
    const u16* hsrc; const int *rs, *csr; u16* out; int T, t;
    int bx = blockIdx.x;
    if (bx < gi) { hsrc = hu; rs = rs_i; csr = csr_i; out = out_i; T = NI;
                   t = bx * 4 + (threadIdx.x >> 6); }
    else         { hsrc = hi; rs = rs_u; csr = csr_u; out = out_u; T = NU;
                   t = (bx - gi) * 4 + (threadIdx.x >> 6); }
    if (t >= T) return;
    const int lane = threadIdx.x & 63;
    const int lr   = lane & 15;        // dims lr*8 .. lr*8+7
    const int sub  = lane >> 4;        // edge slot 0..3
    int e0 = rs[t], e1 = rs[t + 1];
    float acc[8] = {};
    int e = e0 + sub;
    for (; e + 12 < e1; e += 16) {     // 4 rows in flight per slot
        int s0 = __builtin_nontemporal_load(&csr[e]);
        int s1 = __builtin_nontemporal_load(&csr[e + 4]);
        int s2 = __builtin_nontemporal_load(&csr[e + 8]);
        int s3 = __builtin_nontemporal_load(&csr[e + 12]);
        short8 v0 = *(const short8*)&hsrc[(size_t)s0 * 128 + (lr << 3)];
        short8 v1 = *(const short8*)&hsrc[(size_t)s1 * 128 + (lr << 3)];
        short8 v2 = *(const short8*)&hsrc[(size_t)s2 * 128 + (lr << 3)];
        short8 v3 = *(const short8*)&hsrc[(size_t)s3 * 128 + (lr << 3)];
        #pragma unroll
        for (int q = 0; q < 8; ++q)
            acc[q] += (bf2f((u16)v0[q]) + bf2f((u16)v1[q])) +
                      (bf2f((u16)v2[q]) + bf2f((u16)v3[q]));
    }
    for (; e + 4 < e1; e += 8) {
        int s0 = __builtin_nontemporal_load(&csr[e]);
        int s1 = __builtin_nontemporal_load(&csr[e + 4]);
        short8 v0 = *(const short8*)&hsrc[(size_t)s0 * 128 + (lr << 3)];
        short8 v1 = *(const short8*)&hsrc[(size_t)s1 * 128 + (lr << 3)];
        #pragma unroll
        for (int q = 0; q < 8; ++q)
            acc[q] += bf2f((u16)v0[q]) + bf2f((u16)v1[q]);
    }
    if (e < e1) {
        int s0 = __builtin_nontemporal_load(&csr[e]);
        short8 v0 = *(const short8*)&hsrc[(size_t)s0 * 128 + (lr << 3)];
        #pragma unroll
        for (int q = 0; q < 8; ++q) acc[q] += bf2f((u16)v0[q]);
    }
    // reduce across the 4 edge slots (lanes differing in bits 4,5)
    #pragma unroll
    for (int q = 0; q < 8; ++q) {
        acc[q] += __shfl_xor(acc[q], 16);
        acc[q] += __shfl_xor(acc[q], 32);
    }
    if (sub == 0) {
        float inv = (e1 > e0) ? 1.f / (float)(e1 - e0) : 0.f;
        short8 o;
        #pragma unroll
        for (int q = 0; q < 8; ++q) o[q] = (short)f2bf(acc[q] * inv);
        __builtin_nontemporal_store(o, (short8*)&out[(size_t)t * 128 + (lr << 3)]);
    }
}

// ---------------- conv via MFMA, items + users in ONE launch ----------------
// z = [hn|hd] @ Wt^T + bn + bs; relu; row L2-norm.
// Block = 256 threads = 4 waves, 64-row tile. A staged once in LDS (coalesced
// 16B loads, 264-u16 stride). Wave w owns cols [w*16*NF,...), 4 row-frags.
// Epilogue transposes normalized output through LDS -> coalesced 16B stores.
template <int DOUT, bool WRITE_F32>
__global__ __launch_bounds__(256) void conv2_kernel(
    const u16* __restrict__ hn_i, const u16* __restrict__ hd_i,
    const u16* __restrict__ wt_i, const float* __restrict__ bn_i,
    const float* __restrict__ bs_i, float* __restrict__ outf_i,
    u16* __restrict__ outb_i, int ci,
    const u16* __restrict__ hn_u, const u16* __restrict__ hd_u,
    const u16* __restrict__ wt_u, const float* __restrict__ bn_u,
    const float* __restrict__ bs_u, float* __restrict__ outf_u,
    u16* __restrict__ outb_u)
{
    constexpr int NF   = DOUT / 64;               // col fragments per wave (2 or 1)
    constexpr int FSTR = (DOUT == 128) ? 132 : 68; // f32 out stride (16B-aligned rows)
    __shared__ u16 smA[64 * 264];                  // 33792 B, reused as f32 out
    __shared__ float psum[4][64];
    __shared__ float sinv[64];
    float* smF = (float*)smA;

    const u16 *hn, *hd, *Wt; const float *bn, *bs; float* outf; u16* outb; int T, t0;
    if ((int)blockIdx.x < ci) {
        hn = hn_i; hd = hd_i; Wt = wt_i; bn = bn_i; bs = bs_i;
        outf = outf_i; outb = outb_i; T = NI; t0 = blockIdx.x * 64;
    } else {
        hn = hn_u; hd = hd_u; Wt = wt_u; bn = bn_u; bs = bs_u;
        outf = outf_u; outb = outb_u; T = NU; t0 = (blockIdx.x - ci) * 64;
    }

    const int tid  = threadIdx.x;
    const int wave = tid >> 6;
    const int lane = tid & 63;
    const int lr   = lane & 15;
    const int lg   = lane >> 4;                    // 0..3

    // ---- stage A = [hn | hd]: 64 rows x 256 u16, 16B per thread-chunk ----
    #pragma unroll
    for (int i = 0; i < 8; ++i) {
        int lin = i * 256 + tid;                   // 0..2047
        int row = lin >> 5;
        int q   = lin & 31;                        // 16B chunk within row
        int t   = t0 + row; if (t >= T) t = T - 1; // clamp; stores guarded
        const u16* srcp = (q < 16) ? &hn[(size_t)t * 128 + (q << 3)]
                                   : &hd[(size_t)t * 128 + ((q - 16) << 3)];
        *(short8*)&smA[row * 264 + (q << 3)] = *(const short8*)srcp;
    }
    __syncthreads();

    const u16* wp[NF];
    float bias[NF];
    #pragma unroll
    for (int ni = 0; ni < NF; ++ni) {
        int col = wave * (16 * NF) + ni * 16 + lr;
        wp[ni] = Wt + (size_t)col * 256;
        bias[ni] = bn[col] + bs[col];
    }

    f32x4 acc[4][NF];
    #pragma unroll
    for (int mi = 0; mi < 4; ++mi)
        #pragma unroll
        for (int ni = 0; ni < NF; ++ni)
            acc[mi][ni] = (f32x4){0.f, 0.f, 0.f, 0.f};

    #pragma unroll
    for (int ks = 0; ks < 8; ++ks) {
        const int kb = ks * 32 + (lg << 3);
        short8 b[NF];
        #pragma unroll
        for (int ni = 0; ni < NF; ++ni) b[ni] = *(const short8*)&wp[ni][kb];
        #pragma unroll
        for (int mi = 0; mi < 4; ++mi) {
            short8 a = *(const short8*)&smA[(mi * 16 + lr) * 264 + kb];
            #pragma unroll
            for (int ni = 0; ni < NF; ++ni)
                acc[mi][ni] = __builtin_amdgcn_mfma_f32_16x16x32_bf16(a, b[ni], acc[mi][ni], 0, 0, 0);
        }
    }
    __syncthreads();   // all waves done reading smA before overwrite as f32

    // bias + relu; z -> LDS (transpose buffer); per-row partial square-sums
    float rsum[4][4];
    #pragma unroll
    for (int mi = 0; mi < 4; ++mi) {
        #pragma unroll
        for (int j = 0; j < 4; ++j) {
            int rowg = mi * 16 + lg * 4 + j;
            float s = 0.f;
            #pragma unroll
            for (int ni = 0; ni < NF; ++ni) {
                float z = fmaxf(acc[mi][ni][j] + bias[ni], 0.f);
                int colg = wave * (16 * NF) + ni * 16 + lr;
                smF[rowg * FSTR + colg] = z;
                s = fmaf(z, z, s);
            }
            rsum[mi][j] = s;
        }
    }
    #pragma unroll
    for (int m = 1; m < 16; m <<= 1)
        #pragma unroll
        for (int mi = 0; mi < 4; ++mi)
            #pragma unroll
            for (int j = 0; j < 4; ++j)
                rsum[mi][j] += __shfl_xor(rsum[mi][j], m);
    if (lr == 0) {
        #pragma unroll
        for (int mi = 0; mi < 4; ++mi)
            #pragma unroll
            for (int j = 0; j < 4; ++j)
                psum[wave][mi * 16 + lg * 4 + j] = rsum[mi][j];
    }
    __syncthreads();
    if (tid < 64) {
        float n2 = psum[0][tid] + psum[1][tid] + psum[2][tid] + psum[3][tid];
        sinv[tid] = 1.f / fmaxf(sqrtf(n2), 1e-12f);
    }
    __syncthreads();

    // coalesced readback + store: 8 cols (16B bf16 / 32B f32) per thread-task
    constexpr int GPR  = DOUT / 8;           // col groups per row
    constexpr int ITER = 64 * GPR / 256;     // 4 (DOUT=128) or 2 (DOUT=64)
    #pragma unroll
    for (int i = 0; i < ITER; ++i) {
        int lin = i * 256 + tid;
        int row = lin / GPR, g = lin % GPR;
        int t = t0 + row;
        if (t < T) {
            float inv = sinv[row];
            float4 z0 = *(float4*)&smF[row * FSTR + g * 8];
            float4 z1 = *(float4*)&smF[row * FSTR + g * 8 + 4];
            float o0 = z0.x * inv, o1 = z0.y * inv, o2 = z0.z * inv, o3 = z0.w * inv;
            float o4 = z1.x * inv, o5 = z1.y * inv, o6 = z1.z * inv, o7 = z1.w * inv;
            short8 ob = {(short)f2bf(o0), (short)f2bf(o1), (short)f2bf(o2), (short)f2bf(o3),
                         (short)f2bf(o4), (short)f2bf(o5), (short)f2bf(o6), (short)f2bf(o7)};
            *(short8*)&outb[(size_t)t * DOUT + g * 8] = ob;
            if (WRITE_F32) {
                *(float4*)&outf[(size_t)t * DOUT + g * 8]     = (float4){o0, o1, o2, o3};
                *(float4*)&outf[(size_t)t * DOUT + g * 8 + 4] = (float4){o4, o5, o6, o7};
            }
        }
    }
}

// ---------------- cosine scores, pos + neg in ONE launch ----------------
// 8 lanes per pair (8 x ushort8 = 64 dims, 16B/lane); y = pos/neg.
__global__ __launch_bounds__(256) void score2_kernel(
    const u16* __restrict__ hu, const u16* __restrict__ hi,
    const int* __restrict__ pu0, const int* __restrict__ pi0, float* __restrict__ out0,
    const int* __restrict__ pu1, const int* __restrict__ pi1, float* __restrict__ out1,
    int P) {
    const int *pu, *pi; float* out;
    if (blockIdx.y == 0) { pu = pu0; pi = pi0; out = out0; }
    else                 { pu = pu1; pi = pi1; out = out1; }
    int g = threadIdx.x >> 3, l = threadIdx.x & 7;
    int p = blockIdx.x * 32 + g;
    if (p >= P) return;
    int u = __builtin_nontemporal_load(&pu[p]);
    int it = __builtin_nontemporal_load(&pi[p]);
    short8 a = *(const short8*)&hu[(size_t)u * 64 + (l << 3)];
    short8 b = *(const short8*)&hi[(size_t)it * 64 + (l << 3)];
    float d = 0.f, na = 0.f, nb = 0.f;
    #pragma unroll
    for (int q = 0; q < 8; ++q) {
        float x = bf2f((u16)a[q]), y = bf2f((u16)b[q]);
        d  = fmaf(x, y, d);
        na = fmaf(x, x, na);
        nb = fmaf(y, y, nb);
    }
    #pragma unroll
    for (int m = 1; m < 8; m <<= 1) {
        d  += __shfl_xor(d, m);
        na += __shfl_xor(na, m);
        nb += __shfl_xor(nb, m);
    }
    if (l == 0) out[p] = d / (fmaxf(sqrtf(na), 1e-12f) * fmaxf(sqrtf(nb), 1e-12f));
}

// ---------------- host ----------------

extern "C" void kernel_launch(void* const* d_in, const int* in_sizes, int n_in,
                              void* d_out, int out_size, void* d_ws, size_t ws_size,
                              hipStream_t stream) {
    const float* h_user = (const float*)d_in[0];
    const float* h_item = (const float*)d_in[1];
    const float* Wn01   = (const float*)d_in[2];
    const float* bn01   = (const float*)d_in[3];
    const float* Ws01   = (const float*)d_in[4];
    const float* bs01   = (const float*)d_in[5];
    const float* Wn2    = (const float*)d_in[6];
    const float* bn2    = (const float*)d_in[7];
    const float* Ws2    = (const float*)d_in[8];
    const float* bs2    = (const float*)d_in[9];
    const int* u2i_src  = (const int*)d_in[10];
    const int* u2i_dst  = (const int*)d_in[11];
    const int* i2u_src  = (const int*)d_in[12];
    const int* i2u_dst  = (const int*)d_in[13];
    const int* pos_u    = (const int*)d_in[14];
    const int* pos_i    = (const int*)d_in[15];
    const int* neg_u    = (const int*)d_in[16];
    const int* neg_i    = (const int*)d_in[17];

    float* out = (float*)d_out;
    float* out_hu = out;                       // [NU,64]
    float* out_hi = out + (size_t)NU * 64;     // [NI,64]
    float* out_pos = out + (size_t)NU * 64 + (size_t)NI * 64;
    float* out_neg = out_pos + NP;

    // workspace layout
    char* ws = (char*)d_ws;
    size_t off = 0;
    auto alloc = [&](size_t bytes) -> void* {
        void* p = ws + off;
        off = (off + bytes + 255) & ~(size_t)255;
        return p;
    };
    u16* hu0b = (u16*)alloc((size_t)NU * 128 * 2);   // bf16 copies of inputs
    u16* hi0b = (u16*)alloc((size_t)NI * 128 * 2);
    u16* hu_b = (u16*)alloc((size_t)NU * 128 * 2);   // layer intermediates (bf16)
    u16* hi_b = (u16*)alloc((size_t)NI * 128 * 2);
    u16* hu_a = (u16*)alloc((size_t)NU * 128 * 2);
    u16* hi_a = (u16*)alloc((size_t)NI * 128 * 2);
    u16* agg_i = (u16*)alloc((size_t)NI * 128 * 2);  // agg outputs (bf16)
    u16* agg_u = (u16*)alloc((size_t)NU * 128 * 2);
    u16* hu2b = (u16*)alloc((size_t)NU * 64 * 2);    // final embeddings (bf16, scores)
    u16* hi2b = (u16*)alloc((size_t)NI * 64 * 2);
    u16* wt_all = (u16*)alloc((size_t)(4 * 128 * 256 + 2 * 64 * 256) * 2);
    u16* wt_l0_i = wt_all;                 // each 128x256
    u16* wt_l0_u = wt_all + 32768;
    u16* wt_l1_i = wt_all + 65536;
    u16* wt_l1_u = wt_all + 98304;
    u16* wt_l2_i = wt_all + 131072;        // 64x256
    u16* wt_l2_u = wt_all + 147456;
    int* csr_u2i = (int*)alloc((size_t)NE * 4);
    int* csr_i2u = (int*)alloc((size_t)NE * 4);
    int* rs_i   = (int*)alloc((size_t)(NI + 1) * 4);
    int* rs_u   = (int*)alloc((size_t)(NU + 1) * 4);
    int* deg    = (int*)alloc((size_t)(NI + NU) * 4);   // deg_i | deg_u
    int* bsum   = (int*)alloc(1024 * 4);
    int* deg_i = deg, *deg_u = deg + NI;
    // rank arrays alias the (not-yet-live) agg buffers: ranks are produced by
    // hist2 and consumed by fill2, both of which complete before the first
    // agg2 writes agg_i/agg_u (single stream = sequential).
    int* rank_i = (int*)agg_i;   // 4MB <= 12.8MB
    int* rank_u = (int*)agg_u;   // 4MB <= 25.6MB
    (void)ws_size; (void)in_sizes; (void)n_in; (void)out_size;

    const int eblocks = (NE + 255) / 256;

    // ---- bf16 copies of input features + all transposed bf16 weights ----
    cvt_kernel<<<(NU * 128 / 8 + 255) / 256, 256, 0, stream>>>(h_user, hu0b, NU * 128 / 8);
    cvt_kernel<<<(NI * 128 / 8 + 255) / 256, 256, 0, stream>>>(h_item, hi0b, NI * 128 / 8);
    wtrans_all_kernel<<<640, 128, 0, stream>>>(Wn01, Ws01, Wn2, Ws2, wt_all);

    // ---- CSR build (both directions, rank-based single-pass fill) ----
    hipMemsetAsync(deg, 0, (size_t)(NI + NU) * 4, stream);
    hist2_kernel<<<dim3(eblocks, 2), 256, 0, stream>>>(u2i_dst, deg_i, rank_i,
                                                       i2u_dst, deg_u, rank_u, NE);
    {
        int nb = (NI + 1023) / 1024;
        scan_local_kernel<<<nb, 1024, 0, stream>>>(deg_i, rs_i, bsum, NI);
        scan_bsum_kernel<<<1, 1024, 0, stream>>>(bsum, nb);
        scan_finalize_kernel<<<nb, 1024, 0, stream>>>(rs_i, bsum, NI, NE);
    }
    {
        int nb = (NU + 1023) / 1024;
        scan_local_kernel<<<nb, 1024, 0, stream>>>(deg_u, rs_u, bsum, NU);
        scan_bsum_kernel<<<1, 1024, 0, stream>>>(bsum, nb);
        scan_finalize_kernel<<<nb, 1024, 0, stream>>>(rs_u, bsum, NU, NE);
    }
    fill2_kernel<<<dim3(eblocks, 2), 256, 0, stream>>>(
        u2i_src, u2i_dst, rank_i, rs_i, csr_u2i,
        i2u_src, i2u_dst, rank_u, rs_u, csr_i2u, NE);

    const int gi = (NI + 3) / 4, gu = (NU + 3) / 4;          // agg sub-grids
    const int ci = (NI + 63) / 64, cu = (NU + 63) / 64;      // conv sub-grids

    // ---- layer 0 ----
    agg2_kernel<<<gi + gu, 256, 0, stream>>>(hu0b, hi0b, rs_i, csr_u2i, agg_i, gi,
                                             rs_u, csr_i2u, agg_u);
    conv2_kernel<128, false><<<ci + cu, 256, 0, stream>>>(
        agg_i, hi0b, wt_l0_i, bn01 + 0, bs01 + 0, nullptr, hi_b, ci,
        agg_u, hu0b, wt_l0_u, bn01 + 128, bs01 + 128, nullptr, hu_b);
    // ---- layer 1 ----
    agg2_kernel<<<gi + gu, 256, 0, stream>>>(hu_b, hi_b, rs_i, csr_u2i, agg_i, gi,
                                             rs_u, csr_i2u, agg_u);
    conv2_kernel<128, false><<<ci + cu, 256, 0, stream>>>(
        agg_i, hi_b, wt_l1_i, bn01 + 256, bs01 + 256, nullptr, hi_a, ci,
        agg_u, hu_b, wt_l1_u, bn01 + 384, bs01 + 384, nullptr, hu_a);
    // ---- layer 2 (writes d_out embeddings f32 + bf16 copy for scores) ----
    agg2_kernel<<<gi + gu, 256, 0, stream>>>(hu_a, hi_a, rs_i, csr_u2i, agg_i, gi,
                                             rs_u, csr_i2u, agg_u);
    conv2_kernel<64, true><<<ci + cu, 256, 0, stream>>>(
        agg_i, hi_a, wt_l2_i, bn2 + 0, bs2 + 0, out_hi, hi2b, ci,
        agg_u, hu_a, wt_l2_u, bn2 + 64, bs2 + 64, out_hu, hu2b);

    // ---- cosine scores (pos + neg in one launch) ----
    score2_kernel<<<dim3((NP + 31) / 32, 2), 256, 0, stream>>>(
        hu2b, hi2b, pos_u, pos_i, out_pos, neg_u, neg_i, out_neg, NP);
}